// Round 8
// baseline (212.037 us; speedup 1.0000x reference)
//
#include <hip/hip_runtime.h>
#include <math.h>

// B=64, CLN=32, QL=32, IH=16, IW=16, IDF=8192, CDF=256, SL=128
// input : [64][32][32][16][16] fp32 ; context:[64][256][128] fp32 ; W:[8192][256] fp32
// out0: wc fp32 (16777216) ; out1: attnT [64][128][32] fp32 (262144)
//
// k1 v7: 32m x 256n blocks, grid (16 kz, 64 mt) = 1024 blocks = 4 blocks/CU
//        (16 waves/CU of desynced TLP). v6 schedule kept: 2-deep A register
//        pipeline, cvt-before-barrier, write-after-barrier, one s_barrier/iter,
//        setprio around MFMA. B single-buffered (loaded early in-iter).
// k2 v3: padded z-stride (big-ws path) breaks 2MB HBM channel aliasing.
// k0  : merged k0a+k0b single launch (big-ws path).

#define ZK 16

typedef _Float16 f16x8 __attribute__((ext_vector_type(8)));
typedef _Float16 f16x4 __attribute__((ext_vector_type(4)));
typedef __fp16 h16x2 __attribute__((ext_vector_type(2)));
typedef float f32x4 __attribute__((ext_vector_type(4)));

#define GLDS16(gp, lp)                                                          \
    __builtin_amdgcn_global_load_lds(                                           \
        (const __attribute__((address_space(1))) void*)(gp),                    \
        (__attribute__((address_space(3))) void*)(lp), 16, 0, 0)

// ---------------------------------------------------------------------------
// K0a body: W -> Wth/Wtl (k1 B-operand hi/lo, frag-major).
// Frag addr: ((kb*16+nsub)*64 + lane)*8 ; lane=(c&15)+16*((k>>3)&3), j=k&7
// ---------------------------------------------------------------------------
__device__ __forceinline__ void k0a_body(const float* __restrict__ Wm,
                                         _Float16* __restrict__ Wth,
                                         _Float16* __restrict__ Wtl,
                                         int kb, int t, float (*tile)[260]) {
    {
        const int r = t >> 3;           // 0..31
        const int c0 = (t & 7) * 32;    // 0..224
        const float* src = Wm + (long)(kb * 32 + r) * 256 + c0;
#pragma unroll
        for (int i = 0; i < 8; ++i) {
            float4 v = *(const float4*)(src + i * 4);
            tile[r][c0 + i * 4 + 0] = v.x;
            tile[r][c0 + i * 4 + 1] = v.y;
            tile[r][c0 + i * 4 + 2] = v.z;
            tile[r][c0 + i * 4 + 3] = v.w;
        }
    }
    __syncthreads();
    const int lane = t & 63;
    const int quad = lane >> 4, l15 = lane & 15;
#pragma unroll
    for (int i = 0; i < 4; ++i) {
        int nsub = (t >> 6) * 4 + i;    // 0..15
        f16x8 oh, ol;
#pragma unroll
        for (int j = 0; j < 8; ++j) {
            float f = tile[quad * 8 + j][nsub * 16 + l15];
            _Float16 h = (_Float16)f;
            oh[j] = h;
            ol[j] = (_Float16)(f - (float)h);
        }
        long addr = ((long)(kb * 16 + nsub) * 64 + lane) * 8;
        *(f16x8*)(Wth + addr) = oh;
        *(f16x8*)(Wtl + addr) = ol;
    }
}

// ---------------------------------------------------------------------------
// K0b body: W -> Wbf (k4 A-operand fp16, frag-major).
// ---------------------------------------------------------------------------
__device__ __forceinline__ void k0b_body(const float* __restrict__ Wm,
                                         _Float16* __restrict__ Wbf,
                                         int bx, int t) {
    const int fid = bx * 4 + (t >> 6);   // 0..4095
    const int mb = fid >> 3, kb4 = fid & 7;
    const int lane = t & 63;
    const int quad = lane >> 4, l15 = lane & 15;
    const float* src = Wm + (long)(mb * 16 + l15) * 256 + kb4 * 32 + quad * 8;
    float4 u0 = *(const float4*)(src);
    float4 u1 = *(const float4*)(src + 4);
    f16x8 o;
    o[0] = (_Float16)u0.x; o[1] = (_Float16)u0.y;
    o[2] = (_Float16)u0.z; o[3] = (_Float16)u0.w;
    o[4] = (_Float16)u1.x; o[5] = (_Float16)u1.y;
    o[6] = (_Float16)u1.z; o[7] = (_Float16)u1.w;
    *(f16x8*)(Wbf + ((long)fid * 64 + lane) * 8) = o;
}

__global__ __launch_bounds__(256) void k0a_prep(const float* __restrict__ Wm,
                                                _Float16* __restrict__ Wth,
                                                _Float16* __restrict__ Wtl) {
    __shared__ float tile[32][260];
    k0a_body(Wm, Wth, Wtl, blockIdx.x, threadIdx.x, tile);
}
__global__ __launch_bounds__(256) void k0b_prep(const float* __restrict__ Wm,
                                                _Float16* __restrict__ Wbf) {
    k0b_body(Wm, Wbf, blockIdx.x, threadIdx.x);
}
__global__ __launch_bounds__(256) void k0_all(const float* __restrict__ Wm,
                                              _Float16* __restrict__ Wth,
                                              _Float16* __restrict__ Wtl,
                                              _Float16* __restrict__ Wbf) {
    __shared__ float tile[32][260];
    if (blockIdx.x < 256) k0a_body(Wm, Wth, Wtl, blockIdx.x, threadIdx.x, tile);
    else                  k0b_body(Wm, Wbf, blockIdx.x - 256, threadIdx.x);
}

// ---------------------------------------------------------------------------
// K1 v7: tWpart = targetT @ W, fp16 hi/lo 3-pass.
// grid (16 kz, 64 m-tiles of 32) x 256 thr (4 waves; wave tile 32m x 64n).
// 1024 blocks -> 4 blocks/CU -> 16 waves/CU of desynced TLP.
// XCD = (kz + 16*mt)%8 = kz%8 -> 2 kz B-slices per XCD (1 MB, L2-resident).
//
// Per iter (BK=32): issue B(it) [8x b128, oldest -> vmcnt keeps A in flight],
//   issue A(it+2) [1x float4/thread, coalesced 128B per 8-thread row-group],
//   cvt A(it+1) (pkrtz hi/lo, once per element), s_barrier,
//   ds_write_b64 x2 A(it+1)->buf[nxt], ds_read_b128 x4 A(it) frags,
//   lgkmcnt(0), 24 MFMA under setprio. ONE barrier/iter.
// Race-freedom: reads of buf[nxt]@it-1 precede that wave's lgkmcnt(0)@it-1,
// hence barrier(it) -> write@it safe; writes@it precede lgkmcnt(0)@it,
// hence barrier(it+1) -> reads@it+1 safe.
// ---------------------------------------------------------------------------
__global__ __launch_bounds__(256, 4) void k1_mfma(const float* __restrict__ inp,
                                                  const _Float16* __restrict__ Wth,
                                                  const _Float16* __restrict__ Wtl,
                                                  float* __restrict__ tWpart,
                                                  const long zstride) {
    const int kz = blockIdx.x;          // 0..15
    const int m0 = blockIdx.y * 32;     // 64 m-tiles of 32 rows
    const int t = threadIdx.x;
    const int lane = t & 63, wv = t >> 6;
    const int quad = lane >> 4, l15 = lane & 15;

    // [buf][mfrag][lane][j] f16 hi / lo ; buf stride = 1024 elems
    __shared__ _Float16 Fh[2][2][64][8];    // 4 KB
    __shared__ _Float16 Fl[2][2][64][8];    // 4 KB

    // A: thread covers row r = t>>3 (0..31), k-quad kq = t&7 (4 floats)
    const int r_ = t >> 3, kq_ = t & 7;
    const float* arow;
    {
        const int mA = m0 + r_;
        arow = inp + (long)(mA >> 5) * 262144 + (long)(mA & 31) * 256 + kq_ * 4;
    }
    // MFMA A-frag dest: lane' = (r&15) + 16*(kq>>1); j-half = (kq&1)*4
    _Float16* wh = &Fh[0][r_ >> 4][(r_ & 15) + 16 * (kq_ >> 1)][(kq_ & 1) * 4];
    _Float16* wl = &Fl[0][r_ >> 4][(r_ & 15) + 16 * (kq_ >> 1)][(kq_ & 1) * 4];

    f32x4 acc[2][4];
#pragma unroll
    for (int i = 0; i < 2; ++i)
#pragma unroll
        for (int j = 0; j < 4; ++j) acc[i][j] = (f32x4){0.f, 0.f, 0.f, 0.f};

    float4 Ar[2];                       // Ar[it&1] holds A(it)

#define AOFF(kg) ((long)((kg) >> 8) * 8192 + ((kg) & 255))
#define CVT4(a, H, L)                                                           \
    {                                                                           \
        h16x2 h01 = __builtin_amdgcn_cvt_pkrtz(a.x, a.y);                       \
        h16x2 h23 = __builtin_amdgcn_cvt_pkrtz(a.z, a.w);                       \
        h16x2 l01 = __builtin_amdgcn_cvt_pkrtz(a.x - (float)h01[0], a.y - (float)h01[1]); \
        h16x2 l23 = __builtin_amdgcn_cvt_pkrtz(a.z - (float)h23[0], a.w - (float)h23[1]); \
        union { f16x4 v; h16x2 p[2]; } U, V;                                    \
        U.p[0] = h01; U.p[1] = h23;                                             \
        V.p[0] = l01; V.p[1] = l23;                                             \
        H = U.v; L = V.v;                                                       \
    }

    // ---- prologue: load A(0),A(1); cvt+write A(0) -> buf0
    {
        Ar[0] = *(const float4*)(arow + AOFF(kz * 512));
        Ar[1] = *(const float4*)(arow + AOFF(kz * 512 + 32));
        f16x4 H0, L0;
        const float4 a0 = Ar[0];
        CVT4(a0, H0, L0);
        *(f16x4*)(wh) = H0;
        *(f16x4*)(wl) = L0;
        asm volatile("s_waitcnt lgkmcnt(0)" ::: "memory");
        __builtin_amdgcn_sched_barrier(0);
    }

#pragma unroll
    for (int it = 0; it < 16; ++it) {
        const int cur = it & 1, nxt = cur ^ 1;
        // (b) B(it) loads FIRST (oldest in queue -> MFMA waits only on these)
        f16x8 Bh[4], Bl[4];
        {
            const long bb = ((long)((kz * 16 + it) * 16 + wv * 4) * 64 + lane) * 8;
#pragma unroll
            for (int j = 0; j < 4; ++j) {
                Bh[j] = *(const f16x8*)(Wth + bb + (long)j * 512);
                Bl[j] = *(const f16x8*)(Wtl + bb + (long)j * 512);
            }
        }
        // (a) issue A(it+2) -> Ar[cur] (slot free: A(it) was cvt'd at it-1)
        if (it < 14) {
            Ar[cur] = *(const float4*)(arow + AOFF(kz * 512 + (it + 2) * 32));
        }
        __builtin_amdgcn_sched_barrier(0);
        // (c) cvt A(it+1) while other blocks' waves run MFMA
        f16x4 Hn, Ln;
        if (it < 15) {
            const float4 a = Ar[nxt];
            CVT4(a, Hn, Ln);
        }
        __builtin_amdgcn_sched_barrier(0);
        __builtin_amdgcn_s_barrier();       // buf[nxt] free for rewrite
        // (d) ds_write A(it+1) -> buf[nxt]
        if (it < 15) {
            *(f16x4*)(wh + nxt * 1024) = Hn;
            *(f16x4*)(wl + nxt * 1024) = Ln;
        }
        // (e) ds_read buf[cur] frags
        f16x8 ah[2], al[2];
#pragma unroll
        for (int i = 0; i < 2; ++i) {
            ah[i] = *(const f16x8*)&Fh[cur][i][lane][0];
            al[i] = *(const f16x8*)&Fl[cur][i][lane][0];
        }
        asm volatile("s_waitcnt lgkmcnt(0)" ::: "memory");
        __builtin_amdgcn_sched_barrier(0);
        // (f) MFMA: 2 m-frags x 4 n-frags x 3 passes = 24
        __builtin_amdgcn_s_setprio(1);
#pragma unroll
        for (int i = 0; i < 2; ++i)
#pragma unroll
            for (int j = 0; j < 4; ++j)
                acc[i][j] = __builtin_amdgcn_mfma_f32_16x16x32_f16(ah[i], Bh[j], acc[i][j], 0, 0, 0);
#pragma unroll
        for (int i = 0; i < 2; ++i)
#pragma unroll
            for (int j = 0; j < 4; ++j)
                acc[i][j] = __builtin_amdgcn_mfma_f32_16x16x32_f16(al[i], Bh[j], acc[i][j], 0, 0, 0);
#pragma unroll
        for (int i = 0; i < 2; ++i)
#pragma unroll
            for (int j = 0; j < 4; ++j)
                acc[i][j] = __builtin_amdgcn_mfma_f32_16x16x32_f16(ah[i], Bl[j], acc[i][j], 0, 0, 0);
        __builtin_amdgcn_s_setprio(0);
    }

    float* outp = tWpart + (long)kz * zstride;
#pragma unroll
    for (int i = 0; i < 2; ++i) {
        const int mbase = m0 + i * 16 + quad * 4;
#pragma unroll
        for (int j = 0; j < 4; ++j) {
            const int c = (wv * 4 + j) * 16 + l15;
#pragma unroll
            for (int rg = 0; rg < 4; ++rg)
                outp[(long)(mbase + rg) * 256 + c] = acc[i][j][rg];
        }
    }
}

// ---------------------------------------------------------------------------
// K2 v3: reduce split-K partials; logits = tW @ ctx[b]; softmax; write attnT.
// grid (64 b, 8 qg) x 256 thr. XCD = b%8 -> ctx[b] L2-resident per XCD.
// ---------------------------------------------------------------------------
__global__ __launch_bounds__(256) void k2_logits_softmax(const float* __restrict__ tWpart,
                                                         const float* __restrict__ ctx,
                                                         float* __restrict__ attnT,
                                                         const long zstride) {
    const int b  = blockIdx.x;      // 0..63  (fast dim -> XCD = b%8)
    const int qg = blockIdx.y;      // 0..7
    const int t  = threadIdx.x;
    __shared__ float tw4[4][256];
    {
        const int q = t >> 6;               // 0..3
        const int c4 = (t & 63) * 4;        // 0..252
        const float* p = tWpart + (long)(b * 32 + qg * 4 + q) * 256 + c4;
        float4 s = make_float4(0.f, 0.f, 0.f, 0.f);
#pragma unroll
        for (int z = 0; z < ZK; ++z) {
            float4 v = *(const float4*)(p + (long)z * zstride);
            s.x += v.x; s.y += v.y; s.z += v.z; s.w += v.w;
        }
        *(float4*)&tw4[q][c4] = s;
    }
    __syncthreads();
    const int q = t >> 6, lane = t & 63;
    const float* ctxb = ctx + (long)b * 32768 + lane * 2;
    float ax0 = 0.f, ay0 = 0.f, ax1 = 0.f, ay1 = 0.f;
#pragma unroll 8
    for (int c = 0; c < 128; ++c) {
        float twa = tw4[q][c];
        float twb = tw4[q][c + 128];
        float2 cva = *(const float2*)(ctxb + c * 128);
        float2 cvb = *(const float2*)(ctxb + (c + 128) * 128);
        ax0 = fmaf(twa, cva.x, ax0);
        ay0 = fmaf(twa, cva.y, ay0);
        ax1 = fmaf(twb, cvb.x, ax1);
        ay1 = fmaf(twb, cvb.y, ay1);
    }
    float ax = ax0 + ax1, ay = ay0 + ay1;
    float mx = fmaxf(ax, ay);
#pragma unroll
    for (int m = 1; m <= 32; m <<= 1) mx = fmaxf(mx, __shfl_xor(mx, m));
    float ex = expf(ax - mx);
    float ey = expf(ay - mx);
    float sm = ex + ey;
#pragma unroll
    for (int m = 1; m <= 32; m <<= 1) sm += __shfl_xor(sm, m);
    float inv = 1.f / sm;
    ex *= inv; ey *= inv;
    float* o = attnT + (long)b * 4096 + (qg * 4 + q);
    o[(lane * 2 + 0) * 32] = ex;
    o[(lane * 2 + 1) * 32] = ey;
}

// ---------------------------------------------------------------------------
// K3: ctxAqf (frag-major fp16) = ctx @ attn. grid (8 c-chunks, 64 b) x 256.
// ---------------------------------------------------------------------------
__global__ __launch_bounds__(256) void k3_ctxA(const float* __restrict__ ctx,
                                               const float* __restrict__ attnT,
                                               _Float16* __restrict__ ctxAqf) {
    const int cg = blockIdx.x;      // c-chunk of 32
    const int b  = blockIdx.y;
    const int t  = threadIdx.x;
    __shared__ float at[128][32];
    __shared__ float cs[32][132];
#pragma unroll
    for (int i = 0; i < 4; ++i)
        *(float4*)((float*)at + i * 1024 + t * 4) =
            *(const float4*)(attnT + (long)b * 4096 + i * 1024 + t * 4);
#pragma unroll
    for (int i = 0; i < 4; ++i) {
        int idx = i * 256 + t;
        int c = idx >> 5, sseg = (idx & 31) * 4;
        *(float4*)&cs[c][sseg] = *(const float4*)(ctx + (long)b * 32768 + (long)(cg * 32 + c) * 128 + sseg);
    }
    __syncthreads();
    const int c = t >> 3;           // 0..31 (local)
    const int qs = (t & 7) * 4;     // 4 q's
    float4 acc = make_float4(0.f, 0.f, 0.f, 0.f);
#pragma unroll 4
    for (int s = 0; s < 128; ++s) {
        float cv = cs[c][s];
        float4 av = *(const float4*)&at[s][qs];
        acc.x = fmaf(cv, av.x, acc.x);
        acc.y = fmaf(cv, av.y, acc.y);
        acc.z = fmaf(cv, av.z, acc.z);
        acc.w = fmaf(cv, av.w, acc.w);
    }
    const int cglob = cg * 32 + c;
    const long cpart = (long)(cglob >> 5) * 64 + 16 * ((cglob >> 3) & 3);
    float vals[4] = {acc.x, acc.y, acc.z, acc.w};
#pragma unroll
    for (int u = 0; u < 4; ++u) {
        int n = b * 32 + qs + u;
        long addr = ((long)(n >> 4) * 8 * 64 + cpart + (n & 15)) * 8 + (cglob & 7);
        ctxAqf[addr] = (_Float16)vals[u];
    }
}

// ---------------------------------------------------------------------------
// K4 v2: wc = W @ ctxA. grid (128, 16) x 256 thr (4 waves).
// B-panel (64 KB contiguous ctxAqf slice) staged to LDS once per block.
// ---------------------------------------------------------------------------
__global__ __launch_bounds__(256) void k4_mfma(const _Float16* __restrict__ Wbf,
                                               const _Float16* __restrict__ ctxAqf,
                                               float* __restrict__ out0) {
    const int t = threadIdx.x;
    const int lane = t & 63, wv = t >> 6;
    const int mb = blockIdx.x * 4 + wv;     // 0..511 (16 d-rows each)
    const int nb0 = blockIdx.y * 8;         // 8 nb groups of 16 n

    __shared__ _Float16 Bs[32768];          // 64 KB

    {
        const _Float16* gsrc = ctxAqf + (long)nb0 * 4096;
#pragma unroll
        for (int i = 0; i < 16; ++i) {
            const int chunk = i * 256 + wv * 64;            // wave-uniform
            GLDS16(gsrc + (long)chunk * 8 + lane * 8, Bs + chunk * 8);
        }
    }
    __syncthreads();

    const _Float16* abase = Wbf + ((long)mb * 8 * 64 + lane) * 8;

    f32x4 acc[8];
#pragma unroll
    for (int j = 0; j < 8; ++j) acc[j] = (f32x4){0.f, 0.f, 0.f, 0.f};

#pragma unroll
    for (int kb = 0; kb < 8; ++kb) {
        f16x8 af = *(const f16x8*)(abase + (long)kb * 512);
#pragma unroll
        for (int j = 0; j < 8; ++j) {
            f16x8 bf = *(const f16x8*)(Bs + (j * 8 + kb) * 512 + lane * 8);
            acc[j] = __builtin_amdgcn_mfma_f32_16x16x32_f16(af, bf, acc[j], 0, 0, 0);
        }
    }
    const int quad = lane >> 4, col = lane & 15;
#pragma unroll
    for (int j = 0; j < 8; ++j) {
        const int n = (nb0 + j) * 16 + col;
        float* ob = out0 + (long)(n >> 5) * 262144 + (n & 31);
#pragma unroll
        for (int rg = 0; rg < 4; ++rg) {
            const int d = mb * 16 + quad * 4 + rg;
            ob[(long)((d >> 3) & 31) * 8192 + (long)(d >> 8) * 256 + (long)(d & 7) * 32] = acc[j][rg];
        }
    }
}

// ---------------------------------------------------------------------------
extern "C" void kernel_launch(void* const* d_in, const int* in_sizes, int n_in,
                              void* d_out, int out_size, void* d_ws, size_t ws_size,
                              hipStream_t stream) {
    const float* inp = (const float*)d_in[0];
    const float* ctx = (const float*)d_in[1];
    const float* Wm  = (const float*)d_in[2];
    float* out0 = (float*)d_out;
    float* out1 = out0 + 16777216;

    char* wsb = (char*)d_ws;
    const size_t BIG_NEED = 47255552ull;    // padded tWpart + Wth + Wtl + Wbf + ctxAqf

    if (ws_size >= BIG_NEED) {
        // Big-ws layout (47.3 MB), no overlays, padded z-stride:
        const long zs = 524288 + 1088;
        float*    tWpart = (float*)wsb;
        _Float16* Wth    = (_Float16*)(wsb + 33624064);
        _Float16* Wtl    = (_Float16*)(wsb + 37818368);
        _Float16* Wbf    = (_Float16*)(wsb + 42012672);
        _Float16* ctxAqf = (_Float16*)(wsb + 46206976);

        hipLaunchKernelGGL(k0_all, dim3(1280), dim3(256), 0, stream, Wm, Wth, Wtl, Wbf);
        hipLaunchKernelGGL(k1_mfma, dim3(16, 64), dim3(256), 0, stream, inp, Wth, Wtl, tWpart, zs);
        hipLaunchKernelGGL(k2_logits_softmax, dim3(64, 8), dim3(256), 0, stream, tWpart, ctx, out1, zs);
        hipLaunchKernelGGL(k3_ctxA, dim3(8, 64), dim3(256), 0, stream, ctx, out1, ctxAqf);
        hipLaunchKernelGGL(k4_mfma, dim3(128, 16), dim3(256), 0, stream, Wbf, ctxAqf, out0);
    } else {
        // Legacy 40 MB layout (overlaid):
        const long zs = 524288;
        float* wsf = (float*)d_ws;
        float*    tWpart = wsf;
        _Float16* Wbf    = (_Float16*)wsf;
        _Float16* ctxAqf = (_Float16*)(wsf + 1048576);
        _Float16* Wth    = (_Float16*)(wsf + 8388608);
        _Float16* Wtl    = Wth + 2097152;

        hipLaunchKernelGGL(k0a_prep, dim3(256), dim3(256), 0, stream, Wm, Wth, Wtl);
        hipLaunchKernelGGL(k1_mfma, dim3(16, 64), dim3(256), 0, stream, inp, Wth, Wtl, tWpart, zs);
        hipLaunchKernelGGL(k2_logits_softmax, dim3(64, 8), dim3(256), 0, stream, tWpart, ctx, out1, zs);
        hipLaunchKernelGGL(k0b_prep, dim3(1024), dim3(256), 0, stream, Wm, Wbf);
        hipLaunchKernelGGL(k3_ctxA, dim3(8, 64), dim3(256), 0, stream, ctx, out1, ctxAqf);
        hipLaunchKernelGGL(k4_mfma, dim3(128, 16), dim3(256), 0, stream, Wbf, ctxAqf, out0);
    }
}

// Round 9
// 190.408 us; speedup vs baseline: 1.1136x; 1.1136x over previous
//
#include <hip/hip_runtime.h>
#include <math.h>

// B=64, CLN=32, QL=32, IH=16, IW=16, IDF=8192, CDF=256, SL=128
// input : [64][32][32][16][16] fp32 ; context:[64][256][128] fp32 ; W:[8192][256] fp32
// out0: wc fp32 (16777216) ; out1: attnT [64][128][32] fp32 (262144)
//
// k1 v5b (REVERT from v7): 256-thr blocks (4 waves), tile 64m x 256n,
//        grid (16 kz, 32 m) = 512 blocks. A: coalesced loads -> pkrtz hi/lo
//        cvt once -> frag-major f16 LDS dbuf -> ds_read_b128. One barrier/iter.
//        B: reg double-buffered frag stream from L2 (kz%8 XCD-local).
// k2 v4: grid (64 b, 32 q) = 2048 blocks x 128 thr (8 blocks/CU). One block
//        per output row; phase-1 z-reduce float2/thread; phase-2 one s/lane;
//        2-wave softmax via shfl + LDS combine. ctx[b] XCD-local (bid%8=b%8).
// k4 v2: B-panel staged to LDS once per block.

#define ZK 16

typedef _Float16 f16x8 __attribute__((ext_vector_type(8)));
typedef __fp16 h16x2 __attribute__((ext_vector_type(2)));
typedef float f32x4 __attribute__((ext_vector_type(4)));

#define GLDS16(gp, lp)                                                          \
    __builtin_amdgcn_global_load_lds(                                           \
        (const __attribute__((address_space(1))) void*)(gp),                    \
        (__attribute__((address_space(3))) void*)(lp), 16, 0, 0)

// ---------------------------------------------------------------------------
// K0a body: W -> Wth/Wtl (k1 B-operand hi/lo, frag-major).
// Frag addr: ((kb*16+nsub)*64 + lane)*8 ; lane=(c&15)+16*((k>>3)&3), j=k&7
// ---------------------------------------------------------------------------
__device__ __forceinline__ void k0a_body(const float* __restrict__ Wm,
                                         _Float16* __restrict__ Wth,
                                         _Float16* __restrict__ Wtl,
                                         int kb, int t, float (*tile)[260]) {
    {
        const int r = t >> 3;           // 0..31
        const int c0 = (t & 7) * 32;    // 0..224
        const float* src = Wm + (long)(kb * 32 + r) * 256 + c0;
#pragma unroll
        for (int i = 0; i < 8; ++i) {
            float4 v = *(const float4*)(src + i * 4);
            tile[r][c0 + i * 4 + 0] = v.x;
            tile[r][c0 + i * 4 + 1] = v.y;
            tile[r][c0 + i * 4 + 2] = v.z;
            tile[r][c0 + i * 4 + 3] = v.w;
        }
    }
    __syncthreads();
    const int lane = t & 63;
    const int quad = lane >> 4, l15 = lane & 15;
#pragma unroll
    for (int i = 0; i < 4; ++i) {
        int nsub = (t >> 6) * 4 + i;    // 0..15
        f16x8 oh, ol;
#pragma unroll
        for (int j = 0; j < 8; ++j) {
            float f = tile[quad * 8 + j][nsub * 16 + l15];
            _Float16 h = (_Float16)f;
            oh[j] = h;
            ol[j] = (_Float16)(f - (float)h);
        }
        long addr = ((long)(kb * 16 + nsub) * 64 + lane) * 8;
        *(f16x8*)(Wth + addr) = oh;
        *(f16x8*)(Wtl + addr) = ol;
    }
}

// ---------------------------------------------------------------------------
// K0b body: W -> Wbf (k4 A-operand fp16, frag-major).
// ---------------------------------------------------------------------------
__device__ __forceinline__ void k0b_body(const float* __restrict__ Wm,
                                         _Float16* __restrict__ Wbf,
                                         int bx, int t) {
    const int fid = bx * 4 + (t >> 6);   // 0..4095
    const int mb = fid >> 3, kb4 = fid & 7;
    const int lane = t & 63;
    const int quad = lane >> 4, l15 = lane & 15;
    const float* src = Wm + (long)(mb * 16 + l15) * 256 + kb4 * 32 + quad * 8;
    float4 u0 = *(const float4*)(src);
    float4 u1 = *(const float4*)(src + 4);
    f16x8 o;
    o[0] = (_Float16)u0.x; o[1] = (_Float16)u0.y;
    o[2] = (_Float16)u0.z; o[3] = (_Float16)u0.w;
    o[4] = (_Float16)u1.x; o[5] = (_Float16)u1.y;
    o[6] = (_Float16)u1.z; o[7] = (_Float16)u1.w;
    *(f16x8*)(Wbf + ((long)fid * 64 + lane) * 8) = o;
}

__global__ __launch_bounds__(256) void k0a_prep(const float* __restrict__ Wm,
                                                _Float16* __restrict__ Wth,
                                                _Float16* __restrict__ Wtl) {
    __shared__ float tile[32][260];
    k0a_body(Wm, Wth, Wtl, blockIdx.x, threadIdx.x, tile);
}
__global__ __launch_bounds__(256) void k0b_prep(const float* __restrict__ Wm,
                                                _Float16* __restrict__ Wbf) {
    k0b_body(Wm, Wbf, blockIdx.x, threadIdx.x);
}
__global__ __launch_bounds__(256) void k0_all(const float* __restrict__ Wm,
                                              _Float16* __restrict__ Wth,
                                              _Float16* __restrict__ Wtl,
                                              _Float16* __restrict__ Wbf) {
    __shared__ float tile[32][260];
    if (blockIdx.x < 256) k0a_body(Wm, Wth, Wtl, blockIdx.x, threadIdx.x, tile);
    else                  k0b_body(Wm, Wbf, blockIdx.x - 256, threadIdx.x);
}

// ---------------------------------------------------------------------------
// K1 v5b: tWpart = targetT @ W, fp16 hi/lo 3-pass.
// grid (16 kz, 32 m-tiles of 64) x 256 thr (4 waves; wave tile 64m x 64n).
// 512 blocks -> 2 desynced blocks/CU. XCD = kz%8 -> B slice L2-resident.
// Per iter (BK=32): issue A(it+1)+B(it+1) (pinned) | cvt A(it) pkrtz hi/lo |
//   ds_write_b128 x2 | lgkmcnt(0); s_barrier | ds_read_b128 x8 | 48 MFMA.
// ---------------------------------------------------------------------------
__global__ __launch_bounds__(256, 2) void k1_mfma(const float* __restrict__ inp,
                                                  const _Float16* __restrict__ Wth,
                                                  const _Float16* __restrict__ Wtl,
                                                  float* __restrict__ tWpart,
                                                  const long zstride) {
    const int kz = blockIdx.x;          // 0..15
    const int m0 = blockIdx.y * 64;     // 32 m-tiles of 64 rows
    const int t = threadIdx.x;
    const int lane = t & 63, wv = t >> 6;       // wv = n-slice owner (ni)
    const int quad = lane >> 4, l15 = lane & 15;

    // f16 A-frag double-buffer: [buf][m-frag 0..3][slot 0..63][8 halves]
    __shared__ _Float16 Fh[2][4][64][8];    // 8 KB
    __shared__ _Float16 Fl[2][4][64][8];    // 8 KB

    // A: thread covers row m0+(t>>2), k-quad t&3 (8 floats)
    const float* arow;
    {
        const int mA = m0 + (t >> 2);
        arow = inp + (long)(mA >> 5) * 262144 + (long)(mA & 31) * 256 + (t & 3) * 8;
    }
    _Float16* wh = &Fh[0][t >> 6][((t & 3) << 4) | ((t >> 2) & 15)][0];
    _Float16* wl = &Fl[0][t >> 6][((t & 3) << 4) | ((t >> 2) & 15)][0];

    f32x4 acc[4][4];
#pragma unroll
    for (int i = 0; i < 4; ++i)
#pragma unroll
        for (int j = 0; j < 4; ++j) acc[i][j] = (f32x4){0.f, 0.f, 0.f, 0.f};

    float4 Ar[2][2];
    f16x8 Bh[2][4], Bl[2][4];

    // ---- prologue: A(0), B(0)
    {
        const int kg = kz * 512;
        const long off = (long)(kg >> 8) * 8192 + (kg & 255);
        Ar[0][0] = *(const float4*)(arow + off);
        Ar[0][1] = *(const float4*)(arow + off + 4);
        const long bb = ((long)((kz * 16) * 16 + wv * 4) * 64 + lane) * 8;
#pragma unroll
        for (int j = 0; j < 4; ++j) {
            Bh[0][j] = *(const f16x8*)(Wth + bb + (long)j * 512);
            Bl[0][j] = *(const f16x8*)(Wtl + bb + (long)j * 512);
        }
    }

#pragma unroll
    for (int it = 0; it < 16; ++it) {
        const int cur = it & 1, nxt = cur ^ 1;
        // (a) issue next-iter A and B loads (prefetch; pinned below)
        if (it < 15) {
            const int kg = kz * 512 + (it + 1) * 32;
            const long off = (long)(kg >> 8) * 8192 + (kg & 255);
            Ar[nxt][0] = *(const float4*)(arow + off);
            Ar[nxt][1] = *(const float4*)(arow + off + 4);
            const long bb = ((long)((kz * 16 + it + 1) * 16 + wv * 4) * 64 + lane) * 8;
#pragma unroll
            for (int j = 0; j < 4; ++j) {
                Bh[nxt][j] = *(const f16x8*)(Wth + bb + (long)j * 512);
                Bl[nxt][j] = *(const f16x8*)(Wtl + bb + (long)j * 512);
            }
        }
        __builtin_amdgcn_sched_barrier(0);

        // (b) cvt A(it) -> packed hi/lo (pkrtz), converted once per element
        {
            const float4 a0 = Ar[cur][0], a1 = Ar[cur][1];
            h16x2 h01 = __builtin_amdgcn_cvt_pkrtz(a0.x, a0.y);
            h16x2 h23 = __builtin_amdgcn_cvt_pkrtz(a0.z, a0.w);
            h16x2 h45 = __builtin_amdgcn_cvt_pkrtz(a1.x, a1.y);
            h16x2 h67 = __builtin_amdgcn_cvt_pkrtz(a1.z, a1.w);
            h16x2 l01 = __builtin_amdgcn_cvt_pkrtz(a0.x - (float)h01[0], a0.y - (float)h01[1]);
            h16x2 l23 = __builtin_amdgcn_cvt_pkrtz(a0.z - (float)h23[0], a0.w - (float)h23[1]);
            h16x2 l45 = __builtin_amdgcn_cvt_pkrtz(a1.x - (float)h45[0], a1.y - (float)h45[1]);
            h16x2 l67 = __builtin_amdgcn_cvt_pkrtz(a1.z - (float)h67[0], a1.w - (float)h67[1]);
            union { f16x8 v; h16x2 p[4]; } H, L;
            H.p[0] = h01; H.p[1] = h23; H.p[2] = h45; H.p[3] = h67;
            L.p[0] = l01; L.p[1] = l23; L.p[2] = l45; L.p[3] = l67;
            *(f16x8*)(wh + cur * 2048) = H.v;   // ds_write_b128
            *(f16x8*)(wl + cur * 2048) = L.v;   // ds_write_b128
        }
        asm volatile("s_waitcnt lgkmcnt(0)" ::: "memory");
        __builtin_amdgcn_sched_barrier(0);
        __builtin_amdgcn_s_barrier();           // buf[cur] fully written
        __builtin_amdgcn_sched_barrier(0);

        // (c) A-frag reads + MFMA (3 independent passes)
        f16x8 ah[4], al[4];
#pragma unroll
        for (int i = 0; i < 4; ++i) {
            ah[i] = *(const f16x8*)&Fh[cur][i][lane][0];
            al[i] = *(const f16x8*)&Fl[cur][i][lane][0];
        }
#pragma unroll
        for (int i = 0; i < 4; ++i)
#pragma unroll
            for (int j = 0; j < 4; ++j)
                acc[i][j] = __builtin_amdgcn_mfma_f32_16x16x32_f16(ah[i], Bh[cur][j], acc[i][j], 0, 0, 0);
#pragma unroll
        for (int i = 0; i < 4; ++i)
#pragma unroll
            for (int j = 0; j < 4; ++j)
                acc[i][j] = __builtin_amdgcn_mfma_f32_16x16x32_f16(al[i], Bh[cur][j], acc[i][j], 0, 0, 0);
#pragma unroll
        for (int i = 0; i < 4; ++i)
#pragma unroll
            for (int j = 0; j < 4; ++j)
                acc[i][j] = __builtin_amdgcn_mfma_f32_16x16x32_f16(ah[i], Bl[cur][j], acc[i][j], 0, 0, 0);
    }

    float* outp = tWpart + (long)kz * zstride;
#pragma unroll
    for (int i = 0; i < 4; ++i) {
        const int mbase = m0 + i * 16 + quad * 4;
#pragma unroll
        for (int j = 0; j < 4; ++j) {
            const int c = (wv * 4 + j) * 16 + l15;
#pragma unroll
            for (int rg = 0; rg < 4; ++rg)
                outp[(long)(mbase + rg) * 256 + c] = acc[i][j][rg];
        }
    }
}

// ---------------------------------------------------------------------------
// K2 v4: one block per output row (b,q). grid (64 b, 32 q) x 128 thr (2 waves).
// 2048 blocks = 8 blocks/CU (4x the in-flight z-reduce requests of v3).
// XCD = bid%8 = b%8 -> ctx[b] L2-resident per XCD (32 q-blocks co-located).
// Phase 1: z-reduce row (b*32+q): thread t sums float2 at offset 8t across
//          16 slices (16 independent loads in flight).
// Phase 2: lane owns s = t: logit = sum_c tw[c]*ctx[b][c][s], coalesced
//          256B/wave ctx loads, LDS-broadcast tw. 4 FMA chains.
// Softmax over 128 lanes: wave shfl reduce + 2-slot LDS cross-wave combine.
// ---------------------------------------------------------------------------
__global__ __launch_bounds__(128) void k2_logits_softmax(const float* __restrict__ tWpart,
                                                         const float* __restrict__ ctx,
                                                         float* __restrict__ attnT,
                                                         const long zstride) {
    const int b = blockIdx.x;       // 0..63 (fast dim -> XCD = b%8)
    const int q = blockIdx.y;       // 0..31
    const int t = threadIdx.x;      // 0..127
    __shared__ float tw[256];
    __shared__ float red[4];
    // phase 1: z-reduce
    {
        const float* p = tWpart + (long)(b * 32 + q) * 256 + t * 2;
        float sx = 0.f, sy = 0.f;
#pragma unroll
        for (int z = 0; z < ZK; ++z) {
            float2 v = *(const float2*)(p + (long)z * zstride);
            sx += v.x; sy += v.y;
        }
        tw[t * 2] = sx;
        tw[t * 2 + 1] = sy;
    }
    __syncthreads();
    // phase 2: lane owns source position s = t
    const float* ctxb = ctx + (long)b * 32768 + t;
    float a0 = 0.f, a1 = 0.f, a2 = 0.f, a3 = 0.f;
#pragma unroll 2
    for (int c = 0; c < 256; c += 4) {
        a0 = fmaf(tw[c + 0], ctxb[(c + 0) * 128], a0);
        a1 = fmaf(tw[c + 1], ctxb[(c + 1) * 128], a1);
        a2 = fmaf(tw[c + 2], ctxb[(c + 2) * 128], a2);
        a3 = fmaf(tw[c + 3], ctxb[(c + 3) * 128], a3);
    }
    float ax = (a0 + a1) + (a2 + a3);
    // softmax across 128 lanes (2 waves)
    const int wv = t >> 6;
    float mx = ax;
#pragma unroll
    for (int m = 1; m <= 32; m <<= 1) mx = fmaxf(mx, __shfl_xor(mx, m));
    if ((t & 63) == 0) red[wv] = mx;
    __syncthreads();
    mx = fmaxf(red[0], red[1]);
    float ex = expf(ax - mx);
    float sm = ex;
#pragma unroll
    for (int m = 1; m <= 32; m <<= 1) sm += __shfl_xor(sm, m);
    if ((t & 63) == 0) red[2 + wv] = sm;
    __syncthreads();
    sm = red[2] + red[3];
    ex *= (1.f / sm);
    attnT[(long)b * 4096 + t * 32 + q] = ex;
}

// ---------------------------------------------------------------------------
// K3: ctxAqf (frag-major fp16) = ctx @ attn. grid (8 c-chunks, 64 b) x 256.
// ---------------------------------------------------------------------------
__global__ __launch_bounds__(256) void k3_ctxA(const float* __restrict__ ctx,
                                               const float* __restrict__ attnT,
                                               _Float16* __restrict__ ctxAqf) {
    const int cg = blockIdx.x;      // c-chunk of 32
    const int b  = blockIdx.y;
    const int t  = threadIdx.x;
    __shared__ float at[128][32];
    __shared__ float cs[32][132];
#pragma unroll
    for (int i = 0; i < 4; ++i)
        *(float4*)((float*)at + i * 1024 + t * 4) =
            *(const float4*)(attnT + (long)b * 4096 + i * 1024 + t * 4);
#pragma unroll
    for (int i = 0; i < 4; ++i) {
        int idx = i * 256 + t;
        int c = idx >> 5, sseg = (idx & 31) * 4;
        *(float4*)&cs[c][sseg] = *(const float4*)(ctx + (long)b * 32768 + (long)(cg * 32 + c) * 128 + sseg);
    }
    __syncthreads();
    const int c = t >> 3;           // 0..31 (local)
    const int qs = (t & 7) * 4;     // 4 q's
    float4 acc = make_float4(0.f, 0.f, 0.f, 0.f);
#pragma unroll 4
    for (int s = 0; s < 128; ++s) {
        float cv = cs[c][s];
        float4 av = *(const float4*)&at[s][qs];
        acc.x = fmaf(cv, av.x, acc.x);
        acc.y = fmaf(cv, av.y, acc.y);
        acc.z = fmaf(cv, av.z, acc.z);
        acc.w = fmaf(cv, av.w, acc.w);
    }
    const int cglob = cg * 32 + c;
    const long cpart = (long)(cglob >> 5) * 64 + 16 * ((cglob >> 3) & 3);
    float vals[4] = {acc.x, acc.y, acc.z, acc.w};
#pragma unroll
    for (int u = 0; u < 4; ++u) {
        int n = b * 32 + qs + u;
        long addr = ((long)(n >> 4) * 8 * 64 + cpart + (n & 15)) * 8 + (cglob & 7);
        ctxAqf[addr] = (_Float16)vals[u];
    }
}

// ---------------------------------------------------------------------------
// K4 v2: wc = W @ ctxA. grid (128, 16) x 256 thr (4 waves).
// B-panel (64 KB contiguous ctxAqf slice) staged to LDS once per block.
// ---------------------------------------------------------------------------
__global__ __launch_bounds__(256) void k4_mfma(const _Float16* __restrict__ Wbf,
                                               const _Float16* __restrict__ ctxAqf,
                                               float* __restrict__ out0) {
    const int t = threadIdx.x;
    const int lane = t & 63, wv = t >> 6;
    const int mb = blockIdx.x * 4 + wv;     // 0..511 (16 d-rows each)
    const int nb0 = blockIdx.y * 8;         // 8 nb groups of 16 n

    __shared__ _Float16 Bs[32768];          // 64 KB

    {
        const _Float16* gsrc = ctxAqf + (long)nb0 * 4096;
#pragma unroll
        for (int i = 0; i < 16; ++i) {
            const int chunk = i * 256 + wv * 64;            // wave-uniform
            GLDS16(gsrc + (long)chunk * 8 + lane * 8, Bs + chunk * 8);
        }
    }
    __syncthreads();

    const _Float16* abase = Wbf + ((long)mb * 8 * 64 + lane) * 8;

    f32x4 acc[8];
#pragma unroll
    for (int j = 0; j < 8; ++j) acc[j] = (f32x4){0.f, 0.f, 0.f, 0.f};

#pragma unroll
    for (int kb = 0; kb < 8; ++kb) {
        f16x8 af = *(const f16x8*)(abase + (long)kb * 512);
#pragma unroll
        for (int j = 0; j < 8; ++j) {
            f16x8 bf = *(const f16x8*)(Bs + (j * 8 + kb) * 512 + lane * 8);
            acc[j] = __builtin_amdgcn_mfma_f32_16x16x32_f16(af, bf, acc[j], 0, 0, 0);
        }
    }
    const int quad = lane >> 4, col = lane & 15;
#pragma unroll
    for (int j = 0; j < 8; ++j) {
        const int n = (nb0 + j) * 16 + col;
        float* ob = out0 + (long)(n >> 5) * 262144 + (n & 31);
#pragma unroll
        for (int rg = 0; rg < 4; ++rg) {
            const int d = mb * 16 + quad * 4 + rg;
            ob[(long)((d >> 3) & 31) * 8192 + (long)(d >> 8) * 256 + (long)(d & 7) * 32] = acc[j][rg];
        }
    }
}

// ---------------------------------------------------------------------------
extern "C" void kernel_launch(void* const* d_in, const int* in_sizes, int n_in,
                              void* d_out, int out_size, void* d_ws, size_t ws_size,
                              hipStream_t stream) {
    const float* inp = (const float*)d_in[0];
    const float* ctx = (const float*)d_in[1];
    const float* Wm  = (const float*)d_in[2];
    float* out0 = (float*)d_out;
    float* out1 = out0 + 16777216;

    char* wsb = (char*)d_ws;
    const size_t BIG_NEED = 47255552ull;    // padded tWpart + Wth + Wtl + Wbf + ctxAqf

    if (ws_size >= BIG_NEED) {
        // Big-ws layout (47.3 MB), no overlays, padded z-stride:
        const long zs = 524288 + 1088;
        float*    tWpart = (float*)wsb;
        _Float16* Wth    = (_Float16*)(wsb + 33624064);
        _Float16* Wtl    = (_Float16*)(wsb + 37818368);
        _Float16* Wbf    = (_Float16*)(wsb + 42012672);
        _Float16* ctxAqf = (_Float16*)(wsb + 46206976);

        hipLaunchKernelGGL(k0_all, dim3(1280), dim3(256), 0, stream, Wm, Wth, Wtl, Wbf);
        hipLaunchKernelGGL(k1_mfma, dim3(16, 32), dim3(256), 0, stream, inp, Wth, Wtl, tWpart, zs);
        hipLaunchKernelGGL(k2_logits_softmax, dim3(64, 32), dim3(128), 0, stream, tWpart, ctx, out1, zs);
        hipLaunchKernelGGL(k3_ctxA, dim3(8, 64), dim3(256), 0, stream, ctx, out1, ctxAqf);
        hipLaunchKernelGGL(k4_mfma, dim3(128, 16), dim3(256), 0, stream, Wbf, ctxAqf, out0);
    } else {
        // Legacy 40 MB layout (overlaid):
        const long zs = 524288;
        float* wsf = (float*)d_ws;
        float*    tWpart = wsf;
        _Float16* Wbf    = (_Float16*)wsf;
        _Float16* ctxAqf = (_Float16*)(wsf + 1048576);
        _Float16* Wth    = (_Float16*)(wsf + 8388608);
        _Float16* Wtl    = Wth + 2097152;

        hipLaunchKernelGGL(k0a_prep, dim3(256), dim3(256), 0, stream, Wm, Wth, Wtl);
        hipLaunchKernelGGL(k1_mfma, dim3(16, 32), dim3(256), 0, stream, inp, Wth, Wtl, tWpart, zs);
        hipLaunchKernelGGL(k2_logits_softmax, dim3(64, 32), dim3(128), 0, stream, tWpart, ctx, out1, zs);
        hipLaunchKernelGGL(k0b_prep, dim3(1024), dim3(256), 0, stream, Wm, Wbf);
        hipLaunchKernelGGL(k3_ctxA, dim3(8, 64), dim3(256), 0, stream, ctx, out1, ctxAqf);
        hipLaunchKernelGGL(k4_mfma, dim3(128, 16), dim3(256), 0, stream, Wbf, ctxAqf, out0);
    }
}